// Round 3
// baseline (101.042 us; speedup 1.0000x reference)
//
#include <hip/hip_runtime.h>

// Oja scan, algebraically reformulated.
//   c1_t = 1 - lr*y_t^2, c2_t = lr*y_t, P_t = prod_{u<=t} c1_u, a_t = c2_t / P_t
//   pre_t = P_{t-1} * ( G_t + sum_{s<t} a_s * S[s,t] )
// with G_t = W0_row . x_t (per output row) and S[s,t] = x_s . x_t (per batch).
// Kernel 1 (gram): S[b][s][t] -> d_ws (128 KB).
// Kernel 2 (scan): phase 1 computes the 64 independent dots G_t (register-
// resident W row, x from global/L1, no barriers); phase 2 runs the 64-step
// scalar scan with the t-axis spread across lanes: acc[lane] += a_t*S[t,lane].

#define BB 8
#define TT 64
#define NI 1024
#define NO 1024

__device__ __forceinline__ float wave_dot16(const float4* w, const float4* x) {
    float p = 0.0f;
#pragma unroll
    for (int k = 0; k < 4; ++k) {
        p = fmaf(w[k].x, x[k].x, p);
        p = fmaf(w[k].y, x[k].y, p);
        p = fmaf(w[k].z, x[k].z, p);
        p = fmaf(w[k].w, x[k].w, p);
    }
#pragma unroll
    for (int off = 32; off >= 1; off >>= 1)
        p += __shfl_xor(p, off, 64);
    return p;  // full dot, broadcast to all 64 lanes
}

// ---------- Kernel 1: Gram matrix S[b][s][t] = x_s . x_t ----------
__global__ __launch_bounds__(256, 4)
void gram_kernel(const float* __restrict__ X, float* __restrict__ S)
{
    const int lane = threadIdx.x & 63;
    const int wave = threadIdx.x >> 6;
    const int b = blockIdx.x >> 4;                 // 128 blocks: 16 per batch
    const int s = (blockIdx.x & 15) * 4 + wave;    // 0..63
    const float* __restrict__ Xb = X + (size_t)b * TT * NI;

    float4 xs[4];
#pragma unroll
    for (int k = 0; k < 4; ++k)
        xs[k] = *reinterpret_cast<const float4*>(Xb + s * NI + k * 256 + lane * 4);

    float slot = 0.0f;
#pragma unroll 4
    for (int t = 0; t < TT; ++t) {
        float4 xt[4];
#pragma unroll
        for (int k = 0; k < 4; ++k)
            xt[k] = *reinterpret_cast<const float4*>(Xb + t * NI + k * 256 + lane * 4);
        const float p = wave_dot16(xs, xt);
        slot = (lane == t) ? p : slot;
    }
    S[((size_t)b * TT + s) * TT + lane] = slot;    // coalesced row store
}

// ---------- Kernel 2: dots + scalar scan ----------
__global__ __launch_bounds__(512, 8)
void scan_kernel(const float* __restrict__ X, const float* __restrict__ W0,
                 const float* __restrict__ S, float* __restrict__ out)
{
    __shared__ float Sl[TT][TT];   // 16 KB, S[b] staged once

    const int tid  = threadIdx.x;
    const int lane = tid & 63;
    const int wave = tid >> 6;
    const int row  = blockIdx.x * 8 + wave;   // 0..8191
    const int b = row >> 10;                  // 128 blocks per batch
    const int o = row & 1023;

    const float* __restrict__ Xb = X + (size_t)b * TT * NI;

    // stage S[b] (4096 floats; 512 thr x 2 float4, coalesced)
    {
        const float4* __restrict__ src = reinterpret_cast<const float4*>(S + (size_t)b * TT * TT);
        float4* dst = reinterpret_cast<float4*>(&Sl[0][0]);
        dst[tid]       = src[tid];
        dst[tid + 512] = src[tid + 512];
    }

    // W row -> registers (lane l holds elements k*256 + l*4 + j)
    const float* __restrict__ Wrow = W0 + ((size_t)b * NO + o) * NI;
    float4 w[4];
#pragma unroll
    for (int k = 0; k < 4; ++k)
        w[k] = *reinterpret_cast<const float4*>(Wrow + k * 256 + lane * 4);

    // ---- phase 1: 64 independent dots, acc[lane=t] = G_t ----
    float acc = 0.0f;
#pragma unroll 4
    for (int t = 0; t < TT; ++t) {
        float4 xt[4];
#pragma unroll
        for (int k = 0; k < 4; ++k)
            xt[k] = *reinterpret_cast<const float4*>(Xb + t * NI + k * 256 + lane * 4);
        const float g = wave_dot16(w, xt);
        acc = (lane == t) ? g : acc;
    }

    __syncthreads();   // S[b] staged (single barrier in the whole kernel)

    // ---- phase 2: 64-step scalar scan, t-axis across lanes ----
    const float lr = 1.0f / 1024.0f;
    float P = 1.0f;
    float yslot = 0.0f;
    float srow = Sl[0][lane];
#pragma unroll
    for (int t = 0; t < TT; ++t) {
        const float srow_next = (t + 1 < TT) ? Sl[t + 1][lane] : 0.0f;
        const float sg  = __int_as_float(__builtin_amdgcn_readlane(__float_as_int(acc), t));
        const float pre = P * sg;
        const float e   = __expf(-pre);
        const float y   = __builtin_amdgcn_rcpf(1.0f + e);
        yslot = (lane == t) ? y : yslot;
        const float c2 = lr * y;
        const float c1 = fmaf(-c2, y, 1.0f);   // 1 - lr*y^2
        P *= c1;
        const float a = c2 * __builtin_amdgcn_rcpf(P);
        acc = fmaf(a, srow, acc);              // lanes <= t accumulate garbage, never read
        srow = srow_next;
    }

    // out[b][t=lane][o]
    out[(size_t)b * TT * NO + (size_t)lane * NO + o] = yslot;
}

extern "C" void kernel_launch(void* const* d_in, const int* in_sizes, int n_in,
                              void* d_out, int out_size, void* d_ws, size_t ws_size,
                              hipStream_t stream) {
    const float* X  = (const float*)d_in[0];   // [8][64][1024]
    const float* W0 = (const float*)d_in[1];   // [8][1024][1024]
    float* out = (float*)d_out;                // [8][64][1024]
    float* S   = (float*)d_ws;                 // [8][64][64] = 128 KB

    gram_kernel<<<128, 256, 0, stream>>>(X, S);
    scan_kernel<<<1024, 512, 0, stream>>>(X, W0, S, out);
}

// Round 4
// 64.826 us; speedup vs baseline: 1.5587x; 1.5587x over previous
//
#include <hip/hip_runtime.h>
#include <hip/hip_bf16.h>

// Oja scan, reformulated:
//   pre_t = P_{t-1} * ( G_t + sum_{s<t} a_s * S[s,t] ),  a_s = c2_s/P_s,
//   c1=1-lr*y^2, c2=lr*y, P_t = prod c1.
// Kernel 1 (MFMA GEMM): G[b][n][t] for n in [0,1088): rows 0..1023 are W0
// rows (G_t per output), rows 1024..1087 are X rows (=> S = X X^T), all vs
// x_t. bf16 inputs converted on the fly, fp32 accumulate. HBM-stream of W.
// Kernel 2 (scan): per-row 64-step scalar scan, t-axis across lanes.

#define BB 8
#define TT 64
#define NI 1024
#define NO 1024
#define NTOT 1088            // 1024 W rows + 64 X rows
#define NTILES 68            // NTOT/16

typedef __attribute__((ext_vector_type(8))) short bf16x8;
typedef __attribute__((ext_vector_type(4))) float f32x4;

__device__ __forceinline__ short f2bf(float f) {
    __hip_bfloat16 h = __float2bfloat16(f);
    return __builtin_bit_cast(short, h);
}

__device__ __forceinline__ bf16x8 cvt8(const float* __restrict__ p) {
    const float4 lo = *reinterpret_cast<const float4*>(p);
    const float4 hi = *reinterpret_cast<const float4*>(p + 4);
    bf16x8 r;
    r[0] = f2bf(lo.x); r[1] = f2bf(lo.y); r[2] = f2bf(lo.z); r[3] = f2bf(lo.w);
    r[4] = f2bf(hi.x); r[5] = f2bf(hi.y); r[6] = f2bf(hi.z); r[7] = f2bf(hi.w);
    return r;
}

// ---------- Kernel 1: G[b][n][t] = row_n . x_t via MFMA ----------
// Block: 4 waves, one 16-row n-tile, each wave 16 t's. Grid: 8*68 = 544.
__global__ __launch_bounds__(256, 2)
void gemm_kernel(const float* __restrict__ X, const float* __restrict__ W0,
                 float* __restrict__ G)
{
    const int lane = threadIdx.x & 63;
    const int wave = threadIdx.x >> 6;
    const int b  = blockIdx.x / NTILES;
    const int nt = blockIdx.x % NTILES;
    const int n0 = nt * 16;
    const int t0 = wave * 16;

    const int r  = lane & 15;    // row-within-tile (A: n-row, B: t-row)
    const int kb = lane >> 4;    // k-block 0..3, 8 k's each

    const float* __restrict__ Arow =
        (n0 < NO ? W0 + ((size_t)b * NO + n0 + r) * NI
                 : X  + ((size_t)b * TT + (n0 - NO) + r) * NI) + kb * 8;
    const float* __restrict__ Brow =
        X + ((size_t)b * TT + t0 + r) * NI + kb * 8;

    f32x4 acc = {0.f, 0.f, 0.f, 0.f};
#pragma unroll 4
    for (int k0 = 0; k0 < NI; k0 += 32) {
        const bf16x8 a  = cvt8(Arow + k0);
        const bf16x8 bv = cvt8(Brow + k0);
        acc = __builtin_amdgcn_mfma_f32_16x16x32_bf16(a, bv, acc, 0, 0, 0);
    }

    // D layout: col t = lane&15, row n = (lane>>4)*4 + rr   [m89-verified]
    const int tcol = lane & 15;
    const int mrow = (lane >> 4) * 4;
#pragma unroll
    for (int rr = 0; rr < 4; ++rr)
        G[((size_t)b * NTOT + n0 + mrow + rr) * TT + t0 + tcol] = acc[rr];
}

// ---------- Kernel 2: scalar scan per (b,o) row ----------
__global__ __launch_bounds__(512, 8)
void scan_kernel(const float* __restrict__ G, float* __restrict__ out)
{
    __shared__ float Sl[TT][TT];      // 16 KB: S[b]
    __shared__ float ybuf[8][TT + 1]; // per-wave y trajectory (padded)

    const int tid  = threadIdx.x;
    const int lane = tid & 63;
    const int wave = tid >> 6;
    const int row  = blockIdx.x * 8 + wave;   // 0..8191
    const int b = row >> 10;                  // 128 blocks per batch
    const int o = row & 1023;

    // stage S[b] = G rows 1024..1087 (4096 contiguous floats)
    {
        const float4* __restrict__ src =
            reinterpret_cast<const float4*>(G + ((size_t)b * NTOT + NO) * TT);
        float4* dst = reinterpret_cast<float4*>(&Sl[0][0]);
        dst[tid]       = src[tid];
        dst[tid + 512] = src[tid + 512];
    }

    // acc[lane=t] = G_t for this row (contiguous 64 floats)
    float acc = G[((size_t)b * NTOT + o) * TT + lane];

    __syncthreads();

    const float lr = 1.0f / 1024.0f;
    float P = 1.0f;
    float yslot = 0.0f;
    float srow = Sl[0][lane];
#pragma unroll
    for (int t = 0; t < TT; ++t) {
        const float srow_next = (t + 1 < TT) ? Sl[t + 1][lane] : 0.0f;
        const float sg  = __int_as_float(__builtin_amdgcn_readlane(__float_as_int(acc), t));
        const float pre = P * sg;
        const float e   = __expf(-pre);
        const float y   = __builtin_amdgcn_rcpf(1.0f + e);
        yslot = (lane == t) ? y : yslot;
        const float c2 = lr * y;
        const float c1 = fmaf(-c2, y, 1.0f);   // 1 - lr*y^2
        P *= c1;
        const float a = c2 * __builtin_amdgcn_rcpf(P);
        acc = fmaf(a, srow, acc);              // lanes <= t: garbage, never read
        srow = srow_next;
    }

    // coalesce the output: bounce through LDS, then 32B-contiguous stores
    ybuf[wave][lane] = yslot;                  // lane = t
    __syncthreads();
    const int t  = tid >> 3;                   // 0..63
    const int oo = tid & 7;                    // 0..7
    const int o0 = (blockIdx.x & 127) * 8;
    out[(size_t)b * TT * NO + (size_t)t * NO + o0 + oo] = ybuf[oo][t];
}

extern "C" void kernel_launch(void* const* d_in, const int* in_sizes, int n_in,
                              void* d_out, int out_size, void* d_ws, size_t ws_size,
                              hipStream_t stream) {
    const float* X  = (const float*)d_in[0];   // [8][64][1024]
    const float* W0 = (const float*)d_in[1];   // [8][1024][1024]
    float* out = (float*)d_out;                // [8][64][1024]
    float* G   = (float*)d_ws;                 // [8][1088][64] fp32 = 2.23 MB

    gemm_kernel<<<BB * NTILES, 256, 0, stream>>>(X, W0, G);
    scan_kernel<<<1024, 512, 0, stream>>>(G, out);
}